// Round 4
// baseline (225.114 us; speedup 1.0000x reference)
//
#include <hip/hip_runtime.h>
#include <cstdint>

#define BATCHES 8
#define NPTS 2048
#define NF 512
#define KNN 32
#define WAVES 4   // waves per block
#define QPW 2     // queries per wave; block covers 8 queries

// grid = 8 batches * 256 chunks = 2048 blocks; batch = blockIdx & 7 (XCD L2 affinity)
// LDS = 24576 (pts) + 512 (sel) = 25088 B -> 6 blocks/CU resident, ~24 waves/CU.

__global__ __launch_bounds__(256, 6)
void pointnetpp_knn_maxpool(const float* __restrict__ x,
                            const float* __restrict__ points,
                            float* __restrict__ out) {
    __shared__ __align__(16) float pts[NPTS * 3];   // 24 KiB
    __shared__ __align__(16) int   sel[WAVES][KNN]; // 512 B

    const int tid  = threadIdx.x;
    const int lane = tid & 63;
    const int w    = tid >> 6;

    const int b     = blockIdx.x & 7;
    const int chunk = blockIdx.x >> 3;

    // ---- stage points[b] into LDS ----
    {
        const float4* src = (const float4*)(points + (size_t)b * NPTS * 3);
        float4*       dst = (float4*)pts;
        #pragma unroll
        for (int k = 0; k < (NPTS * 3 / 4) / 256; ++k)
            dst[tid + k * 256] = src[tid + k * 256];
    }
    __syncthreads();

    const uint64_t lmlt = (1ull << lane) - 1ull;
    const float*   xb   = x + (size_t)b * NPTS * NF;

    for (int q = 0; q < QPW; ++q) {
        const int i = chunk * (WAVES * QPW) + w * QPW + q;

        const float qx = pts[i * 3 + 0];
        const float qy = pts[i * 3 + 1];
        const float qz = pts[i * 3 + 2];

        // ---- squared distances (bit patterns; identical arithmetic to R1/R3) ----
        uint32_t db[32];
        #pragma unroll
        for (int j = 0; j < 32; ++j) {
            const int n = lane + (j << 6);
            const float dx = qx - pts[n * 3 + 0];
            const float dy = qy - pts[n * 3 + 1];
            const float dz = qz - pts[n * 3 + 2];
            const float d2 = dx * dx + dy * dy + dz * dz;
            db[j] = __float_as_uint(d2);
        }

        // ---- seed hi = wave_max(per-lane min): count(<=hi) >= 64 ----
        uint32_t lmin = db[0];
        #pragma unroll
        for (int j = 1; j < 32; ++j) lmin = min(lmin, db[j]);
        uint32_t hi = lmin;
        #pragma unroll
        for (int m = 1; m < 64; m <<= 1)
            hi = max(hi, (uint32_t)__shfl_xor((int)hi, m));
        uint32_t lo = 0u;   // count(<=0) = 1 (self) < KNN

        // ---- binary search on bit patterns; early exit when count == KNN ----
        uint32_t bound = 0u;
        bool     found = false;
        while (hi - lo > 1u) {
            const uint32_t mid = lo + ((hi - lo) >> 1);
            uint32_t c = 0;
            #pragma unroll
            for (int j = 0; j < 32; ++j)
                c += (uint32_t)__builtin_popcountll(__ballot(db[j] <= mid));
            if (c == KNN) { bound = mid; found = true; break; }
            if (c > KNN) hi = mid; else lo = mid;
        }

        if (found) {
            // exact top-32 set is {v <= bound}; order-free compaction
            uint32_t base = 0;
            #pragma unroll
            for (int j = 0; j < 32; ++j) {
                const uint64_t m = __ballot(db[j] <= bound);
                if (db[j] <= bound) {
                    const int slot = (int)base + (int)__popcll(m & lmlt);
                    sel[w][slot] = lane + (j << 6);
                }
                base += (uint32_t)__builtin_popcountll(m);
            }
        } else {
            // exact-tie fallback: T = hi; all <T, then ==T in ascending-n order
            const uint32_t T = hi;
            uint32_t cl = 0;
            #pragma unroll
            for (int j = 0; j < 32; ++j)
                cl += (uint32_t)__builtin_popcountll(__ballot(db[j] <= lo));
            const int cnt_lt = (int)cl;
            int base_lt = 0, base_eq = 0;
            #pragma unroll
            for (int j = 0; j < 32; ++j) {
                const bool lt = db[j] < T;
                const bool eq = db[j] == T;
                const uint64_t mlt = __ballot(lt);
                const uint64_t meq = __ballot(eq);
                int slot = -1;
                if (lt)      slot = base_lt + (int)__popcll(mlt & lmlt);
                else if (eq) slot = cnt_lt + base_eq + (int)__popcll(meq & lmlt);
                if (slot >= 0 && slot < KNN) sel[w][slot] = lane + (j << 6);
                base_lt += (int)__popcll(mlt);
                base_eq += (int)__popcll(meq);
            }
        }

        // ---- gather + max-pool: one LDS read, then readlane broadcasts ----
        const int selv = sel[w][lane & (KNN - 1)];   // lanes 0..31 hold slots 0..31

        float4 a0 = make_float4(-INFINITY, -INFINITY, -INFINITY, -INFINITY);
        float4 a1 = a0;
        #pragma unroll 8
        for (int k = 0; k < KNN; ++k) {
            const int nb = __builtin_amdgcn_readlane(selv, k) & (NPTS - 1);
            const float4* row = (const float4*)(xb + (size_t)nb * NF);
            const float4 v0 = row[lane];
            const float4 v1 = row[lane + 64];
            a0.x = fmaxf(a0.x, v0.x);  a0.y = fmaxf(a0.y, v0.y);
            a0.z = fmaxf(a0.z, v0.z);  a0.w = fmaxf(a0.w, v0.w);
            a1.x = fmaxf(a1.x, v1.x);  a1.y = fmaxf(a1.y, v1.y);
            a1.z = fmaxf(a1.z, v1.z);  a1.w = fmaxf(a1.w, v1.w);
        }

        float4* orow = (float4*)(out + ((size_t)b * NPTS + i) * NF);
        orow[lane]      = a0;
        orow[lane + 64] = a1;
    }
}

extern "C" void kernel_launch(void* const* d_in, const int* in_sizes, int n_in,
                              void* d_out, int out_size, void* d_ws, size_t ws_size,
                              hipStream_t stream) {
    const float* x      = (const float*)d_in[0];   // [8, 2048, 512] f32
    const float* points = (const float*)d_in[1];   // [8, 2048, 3]   f32
    float* out          = (float*)d_out;           // [8, 2048, 512] f32

    pointnetpp_knn_maxpool<<<dim3(BATCHES * (NPTS / (WAVES * QPW))),
                             dim3(256), 0, stream>>>(x, points, out);
}

// Round 5
// 170.789 us; speedup vs baseline: 1.3181x; 1.3181x over previous
//
#include <hip/hip_runtime.h>
#include <cstdint>

#define BATCHES 8
#define NPTS 2048
#define NF 512
#define KNN 32
#define WAVES 4   // waves per block
#define QPW 2     // queries per wave; block covers 8 queries

// grid = 8 batches * 256 chunks = 2048 blocks; batch = blockIdx & 7 (XCD L2 affinity)
// LDS = 24576 (pts) + 512 (sel) = 25088 B -> 6 blocks/CU (LDS-limited) if VGPR <= 85.
// __launch_bounds__(256,4): R4's (256,6) made the allocator spill db[32] to
// scratch (VGPR 40, +300 MB TCC traffic). (256,4) compiled this structure at
// 64 VGPR with no spill in R1.

__global__ __launch_bounds__(256, 4)
void pointnetpp_knn_maxpool(const float* __restrict__ x,
                            const float* __restrict__ points,
                            float* __restrict__ out) {
    __shared__ __align__(16) float pts[NPTS * 3];   // 24 KiB
    __shared__ __align__(16) int   sel[WAVES][KNN]; // 512 B

    const int tid  = threadIdx.x;
    const int lane = tid & 63;
    const int w    = tid >> 6;

    const int b     = blockIdx.x & 7;
    const int chunk = blockIdx.x >> 3;

    // ---- stage points[b] into LDS ----
    {
        const float4* src = (const float4*)(points + (size_t)b * NPTS * 3);
        float4*       dst = (float4*)pts;
        #pragma unroll
        for (int k = 0; k < (NPTS * 3 / 4) / 256; ++k)
            dst[tid + k * 256] = src[tid + k * 256];
    }
    __syncthreads();

    const uint64_t lmlt = (1ull << lane) - 1ull;
    const float*   xb   = x + (size_t)b * NPTS * NF;

    for (int q = 0; q < QPW; ++q) {
        const int i = chunk * (WAVES * QPW) + w * QPW + q;

        const float qx = pts[i * 3 + 0];
        const float qy = pts[i * 3 + 1];
        const float qz = pts[i * 3 + 2];

        // ---- squared distances (bit patterns; identical arithmetic to R1/R3) ----
        uint32_t db[32];
        #pragma unroll
        for (int j = 0; j < 32; ++j) {
            const int n = lane + (j << 6);
            const float dx = qx - pts[n * 3 + 0];
            const float dy = qy - pts[n * 3 + 1];
            const float dz = qz - pts[n * 3 + 2];
            const float d2 = dx * dx + dy * dy + dz * dz;
            db[j] = __float_as_uint(d2);
        }

        // ---- seed hi = wave_max(per-lane min): count(<=hi) >= 64 ----
        uint32_t lmin = db[0];
        #pragma unroll
        for (int j = 1; j < 32; ++j) lmin = min(lmin, db[j]);
        uint32_t hi = lmin;
        #pragma unroll
        for (int m = 1; m < 64; m <<= 1)
            hi = max(hi, (uint32_t)__shfl_xor((int)hi, m));
        uint32_t lo = 0u;   // count(<=0) = 1 (self) < KNN

        // ---- binary search on bit patterns; early exit when count == KNN ----
        uint32_t bound = 0u;
        bool     found = false;
        while (hi - lo > 1u) {
            const uint32_t mid = lo + ((hi - lo) >> 1);
            uint32_t c = 0;
            #pragma unroll
            for (int j = 0; j < 32; ++j)
                c += (uint32_t)__builtin_popcountll(__ballot(db[j] <= mid));
            if (c == KNN) { bound = mid; found = true; break; }
            if (c > KNN) hi = mid; else lo = mid;
        }

        if (found) {
            // exact top-32 set is {v <= bound}; order-free compaction
            uint32_t base = 0;
            #pragma unroll
            for (int j = 0; j < 32; ++j) {
                const uint64_t m = __ballot(db[j] <= bound);
                if (db[j] <= bound) {
                    const int slot = (int)base + (int)__popcll(m & lmlt);
                    sel[w][slot] = lane + (j << 6);
                }
                base += (uint32_t)__builtin_popcountll(m);
            }
        } else {
            // exact-tie fallback: T = hi; all <T, then ==T in ascending-n order
            // (loop exited naturally => lo == hi-1 => count(<=lo) == count(<T))
            const uint32_t T = hi;
            uint32_t cl = 0;
            #pragma unroll
            for (int j = 0; j < 32; ++j)
                cl += (uint32_t)__builtin_popcountll(__ballot(db[j] <= lo));
            const int cnt_lt = (int)cl;
            int base_lt = 0, base_eq = 0;
            #pragma unroll
            for (int j = 0; j < 32; ++j) {
                const bool lt = db[j] < T;
                const bool eq = db[j] == T;
                const uint64_t mlt = __ballot(lt);
                const uint64_t meq = __ballot(eq);
                int slot = -1;
                if (lt)      slot = base_lt + (int)__popcll(mlt & lmlt);
                else if (eq) slot = cnt_lt + base_eq + (int)__popcll(meq & lmlt);
                if (slot >= 0 && slot < KNN) sel[w][slot] = lane + (j << 6);
                base_lt += (int)__popcll(mlt);
                base_eq += (int)__popcll(meq);
            }
        }

        // ---- gather + max-pool: one LDS read, then readlane broadcasts ----
        const int selv = sel[w][lane & (KNN - 1)];   // lanes 0..31 hold slots 0..31

        float4 a0 = make_float4(-INFINITY, -INFINITY, -INFINITY, -INFINITY);
        float4 a1 = a0;
        #pragma unroll 8
        for (int k = 0; k < KNN; ++k) {
            const int nb = __builtin_amdgcn_readlane(selv, k) & (NPTS - 1);
            const float4* row = (const float4*)(xb + (size_t)nb * NF);
            const float4 v0 = row[lane];
            const float4 v1 = row[lane + 64];
            a0.x = fmaxf(a0.x, v0.x);  a0.y = fmaxf(a0.y, v0.y);
            a0.z = fmaxf(a0.z, v0.z);  a0.w = fmaxf(a0.w, v0.w);
            a1.x = fmaxf(a1.x, v1.x);  a1.y = fmaxf(a1.y, v1.y);
            a1.z = fmaxf(a1.z, v1.z);  a1.w = fmaxf(a1.w, v1.w);
        }

        float4* orow = (float4*)(out + ((size_t)b * NPTS + i) * NF);
        orow[lane]      = a0;
        orow[lane + 64] = a1;
    }
}

extern "C" void kernel_launch(void* const* d_in, const int* in_sizes, int n_in,
                              void* d_out, int out_size, void* d_ws, size_t ws_size,
                              hipStream_t stream) {
    const float* x      = (const float*)d_in[0];   // [8, 2048, 512] f32
    const float* points = (const float*)d_in[1];   // [8, 2048, 3]   f32
    float* out          = (float*)d_out;           // [8, 2048, 512] f32

    pointnetpp_knn_maxpool<<<dim3(BATCHES * (NPTS / (WAVES * QPW))),
                             dim3(256), 0, stream>>>(x, points, out);
}

// Round 7
// 144.460 us; speedup vs baseline: 1.5583x; 1.1823x over previous
//
#include <hip/hip_runtime.h>
#include <cstdint>

#define BATCHES 8
#define NPTS 2048
#define NF 512
#define KNN 32
#define WAVES 4   // waves per block
#define QPW 2     // queries per wave, processed INTERLEAVED (dual-stream ILP)

// grid = 8 batches * 256 chunks = 2048 blocks; batch = blockIdx & 7 (XCD L2 affinity)
// LDS = 24576 (pts) + 1024 (sel) = 25600 B.
// (256,4): R4 showed tighter bounds spill db[] to scratch (+300MB TCC traffic).

typedef float vfloat4 __attribute__((ext_vector_type(4)));  // native vec for nt-store

__global__ __launch_bounds__(256, 4)
void pointnetpp_knn_maxpool(const float* __restrict__ x,
                            const float* __restrict__ points,
                            float* __restrict__ out) {
    __shared__ __align__(16) float pts[NPTS * 3];      // 24 KiB
    __shared__ __align__(16) int   sel[WAVES][2][KNN]; // 1 KiB

    const int tid  = threadIdx.x;
    const int lane = tid & 63;
    const int w    = tid >> 6;

    const int b     = blockIdx.x & 7;
    const int chunk = blockIdx.x >> 3;

    // ---- stage points[b] into LDS ----
    {
        const float4* src = (const float4*)(points + (size_t)b * NPTS * 3);
        float4*       dst = (float4*)pts;
        #pragma unroll
        for (int k = 0; k < (NPTS * 3 / 4) / 256; ++k)
            dst[tid + k * 256] = src[tid + k * 256];
    }
    __syncthreads();

    const uint64_t lmlt = (1ull << lane) - 1ull;
    const float*   xb   = x + (size_t)b * NPTS * NF;

    const int iA = chunk * (WAVES * QPW) + w * QPW;
    const int iB = iA + 1;

    const float qxA = pts[iA * 3 + 0], qyA = pts[iA * 3 + 1], qzA = pts[iA * 3 + 2];
    const float qxB = pts[iB * 3 + 0], qyB = pts[iB * 3 + 1], qzB = pts[iB * 3 + 2];

    // ---- squared distances for BOTH queries; one pts read feeds both ----
    uint32_t dbA[32], dbB[32];
    #pragma unroll
    for (int j = 0; j < 32; ++j) {
        const int n = lane + (j << 6);
        const float px = pts[n * 3 + 0];
        const float py = pts[n * 3 + 1];
        const float pz = pts[n * 3 + 2];
        const float dxA = qxA - px, dyA = qyA - py, dzA = qzA - pz;
        const float dxB = qxB - px, dyB = qyB - py, dzB = qzB - pz;
        dbA[j] = __float_as_uint(dxA * dxA + dyA * dyA + dzA * dzA);
        dbB[j] = __float_as_uint(dxB * dxB + dyB * dyB + dzB * dzB);
    }

    // ---- seeds: hi = wave_max(per-lane min) for each stream ----
    uint32_t lminA = dbA[0], lminB = dbB[0];
    #pragma unroll
    for (int j = 1; j < 32; ++j) { lminA = min(lminA, dbA[j]); lminB = min(lminB, dbB[j]); }
    uint32_t hiA = lminA, hiB = lminB;
    #pragma unroll
    for (int m = 1; m < 64; m <<= 1) {
        hiA = max(hiA, (uint32_t)__shfl_xor((int)hiA, m));
        hiB = max(hiB, (uint32_t)__shfl_xor((int)hiB, m));
    }
    uint32_t loA = 0u, loB = 0u;

    // ---- dual lock-step binary search; early exit per stream on count==KNN ----
    uint32_t boundA = 0u, boundB = 0u;
    bool foundA = false, foundB = false;
    while (true) {
        const bool runA = !foundA && (hiA - loA > 1u);
        const bool runB = !foundB && (hiB - loB > 1u);
        if (!runA && !runB) break;
        const uint32_t midA = loA + ((hiA - loA) >> 1);
        const uint32_t midB = loB + ((hiB - loB) >> 1);
        uint32_t cA = 0, cB = 0;
        if (runA && runB) {
            #pragma unroll
            for (int j = 0; j < 32; ++j) {
                cA += (uint32_t)__builtin_popcountll(__ballot(dbA[j] <= midA));
                cB += (uint32_t)__builtin_popcountll(__ballot(dbB[j] <= midB));
            }
        } else if (runA) {
            #pragma unroll
            for (int j = 0; j < 32; ++j)
                cA += (uint32_t)__builtin_popcountll(__ballot(dbA[j] <= midA));
        } else {
            #pragma unroll
            for (int j = 0; j < 32; ++j)
                cB += (uint32_t)__builtin_popcountll(__ballot(dbB[j] <= midB));
        }
        if (runA) {
            if (cA == KNN) { boundA = midA; foundA = true; }
            else if (cA > KNN) hiA = midA; else loA = midA;
        }
        if (runB) {
            if (cB == KNN) { boundB = midB; foundB = true; }
            else if (cB > KNN) hiB = midB; else loB = midB;
        }
    }

    // ---- emit (identical semantics to R5, per stream) ----
    #pragma unroll
    for (int s = 0; s < 2; ++s) {
        const uint32_t* db    = s ? dbB : dbA;
        const bool      found = s ? foundB : foundA;
        const uint32_t  bound = s ? boundB : boundA;
        const uint32_t  lo    = s ? loB : loA;
        const uint32_t  hi    = s ? hiB : hiA;
        if (found) {
            uint32_t base = 0;
            #pragma unroll
            for (int j = 0; j < 32; ++j) {
                const uint64_t m = __ballot(db[j] <= bound);
                if (db[j] <= bound) {
                    const int slot = (int)base + (int)__popcll(m & lmlt);
                    sel[w][s][slot] = lane + (j << 6);
                }
                base += (uint32_t)__builtin_popcountll(m);
            }
        } else {
            const uint32_t T = hi;
            uint32_t cl = 0;
            #pragma unroll
            for (int j = 0; j < 32; ++j)
                cl += (uint32_t)__builtin_popcountll(__ballot(db[j] <= lo));
            const int cnt_lt = (int)cl;
            int base_lt = 0, base_eq = 0;
            #pragma unroll
            for (int j = 0; j < 32; ++j) {
                const bool lt = db[j] < T;
                const bool eq = db[j] == T;
                const uint64_t mlt = __ballot(lt);
                const uint64_t meq = __ballot(eq);
                int slot = -1;
                if (lt)      slot = base_lt + (int)__popcll(mlt & lmlt);
                else if (eq) slot = cnt_lt + base_eq + (int)__popcll(meq & lmlt);
                if (slot >= 0 && slot < KNN) sel[w][s][slot] = lane + (j << 6);
                base_lt += (int)__popcll(mlt);
                base_eq += (int)__popcll(meq);
            }
        }
    }

    // ---- dual gather + max-pool: 4 loads in flight per k, 2 fmax streams ----
    const int selvA = sel[w][0][lane & (KNN - 1)];
    const int selvB = sel[w][1][lane & (KNN - 1)];

    float4 a0 = make_float4(-INFINITY, -INFINITY, -INFINITY, -INFINITY);
    float4 a1 = a0, b0 = a0, b1 = a0;
    #pragma unroll 4
    for (int k = 0; k < KNN; ++k) {
        const int nA = __builtin_amdgcn_readlane(selvA, k) & (NPTS - 1);
        const int nB = __builtin_amdgcn_readlane(selvB, k) & (NPTS - 1);
        const float4* rowA = (const float4*)(xb + (size_t)nA * NF);
        const float4* rowB = (const float4*)(xb + (size_t)nB * NF);
        const float4 vA0 = rowA[lane];
        const float4 vA1 = rowA[lane + 64];
        const float4 vB0 = rowB[lane];
        const float4 vB1 = rowB[lane + 64];
        a0.x = fmaxf(a0.x, vA0.x); a0.y = fmaxf(a0.y, vA0.y);
        a0.z = fmaxf(a0.z, vA0.z); a0.w = fmaxf(a0.w, vA0.w);
        a1.x = fmaxf(a1.x, vA1.x); a1.y = fmaxf(a1.y, vA1.y);
        a1.z = fmaxf(a1.z, vA1.z); a1.w = fmaxf(a1.w, vA1.w);
        b0.x = fmaxf(b0.x, vB0.x); b0.y = fmaxf(b0.y, vB0.y);
        b0.z = fmaxf(b0.z, vB0.z); b0.w = fmaxf(b0.w, vB0.w);
        b1.x = fmaxf(b1.x, vB1.x); b1.y = fmaxf(b1.y, vB1.y);
        b1.z = fmaxf(b1.z, vB1.z); b1.w = fmaxf(b1.w, vB1.w);
    }

    // ---- nontemporal stores (native ext_vector_type): no L2 write-allocate ----
    vfloat4* orowA = (vfloat4*)(out + ((size_t)b * NPTS + iA) * NF);
    vfloat4* orowB = (vfloat4*)(out + ((size_t)b * NPTS + iB) * NF);
    const vfloat4 na0 = vfloat4{a0.x, a0.y, a0.z, a0.w};
    const vfloat4 na1 = vfloat4{a1.x, a1.y, a1.z, a1.w};
    const vfloat4 nb0 = vfloat4{b0.x, b0.y, b0.z, b0.w};
    const vfloat4 nb1 = vfloat4{b1.x, b1.y, b1.z, b1.w};
    __builtin_nontemporal_store(na0, &orowA[lane]);
    __builtin_nontemporal_store(na1, &orowA[lane + 64]);
    __builtin_nontemporal_store(nb0, &orowB[lane]);
    __builtin_nontemporal_store(nb1, &orowB[lane + 64]);
}

extern "C" void kernel_launch(void* const* d_in, const int* in_sizes, int n_in,
                              void* d_out, int out_size, void* d_ws, size_t ws_size,
                              hipStream_t stream) {
    const float* x      = (const float*)d_in[0];   // [8, 2048, 512] f32
    const float* points = (const float*)d_in[1];   // [8, 2048, 3]   f32
    float* out          = (float*)d_out;           // [8, 2048, 512] f32

    pointnetpp_knn_maxpool<<<dim3(BATCHES * (NPTS / (WAVES * QPW))),
                             dim3(256), 0, stream>>>(x, points, out);
}

// Round 8
// 134.195 us; speedup vs baseline: 1.6775x; 1.0765x over previous
//
#include <hip/hip_runtime.h>
#include <cstdint>

#define BATCHES 8
#define NPTS 2048
#define NF 512
#define KNN 32
#define WAVES 8   // 512-thread block = 8 waves, ONE query per wave

// grid = 8 batches * 256 chunks = 2048 blocks; batch = blockIdx & 7 (XCD L2 affinity)
// Residency: 4 blocks/CU (32-wave cap) x 8 waves = 8 waves/SIMD if VGPR <= 64.
// LDS = 24576 (pts) + 1024 (sel) = 25600 B -> 4 blocks = 100 KB < 160 KB. OK.
// (512,4): loose VGPR cap (128) -- R4 showed tight caps trigger catastrophic
// scratch spill of db[32]; R5's identical body compiled naturally to 64.

typedef float vfloat4 __attribute__((ext_vector_type(4)));  // native vec for nt-store

__global__ __launch_bounds__(512, 4)
void pointnetpp_knn_maxpool(const float* __restrict__ x,
                            const float* __restrict__ points,
                            float* __restrict__ out) {
    __shared__ __align__(16) float pts[NPTS * 3];     // 24 KiB
    __shared__ __align__(16) int   sel[WAVES][KNN];   // 1 KiB

    const int tid  = threadIdx.x;
    const int lane = tid & 63;
    const int w    = tid >> 6;

    const int b     = blockIdx.x & 7;
    const int chunk = blockIdx.x >> 3;

    // ---- stage points[b] into LDS (512 threads, 3 iters) ----
    {
        const float4* src = (const float4*)(points + (size_t)b * NPTS * 3);
        float4*       dst = (float4*)pts;
        #pragma unroll
        for (int k = 0; k < (NPTS * 3 / 4) / 512; ++k)
            dst[tid + k * 512] = src[tid + k * 512];
    }
    __syncthreads();

    const uint64_t lmlt = (1ull << lane) - 1ull;
    const float*   xb   = x + (size_t)b * NPTS * NF;

    const int i = chunk * WAVES + w;   // this wave's query

    const float qx = pts[i * 3 + 0];
    const float qy = pts[i * 3 + 1];
    const float qz = pts[i * 3 + 2];

    // ---- squared distances (bit patterns; identical arithmetic to R1..R7) ----
    uint32_t db[32];
    #pragma unroll
    for (int j = 0; j < 32; ++j) {
        const int n = lane + (j << 6);
        const float dx = qx - pts[n * 3 + 0];
        const float dy = qy - pts[n * 3 + 1];
        const float dz = qz - pts[n * 3 + 2];
        const float d2 = dx * dx + dy * dy + dz * dz;
        db[j] = __float_as_uint(d2);
    }

    // ---- seed hi = wave_max(per-lane min): count(<=hi) >= 64 ----
    uint32_t lmin = db[0];
    #pragma unroll
    for (int j = 1; j < 32; ++j) lmin = min(lmin, db[j]);
    uint32_t hi = lmin;
    #pragma unroll
    for (int m = 1; m < 64; m <<= 1)
        hi = max(hi, (uint32_t)__shfl_xor((int)hi, m));
    uint32_t lo = 0u;   // count(<=0) = 1 (self) < KNN

    // ---- binary search on bit patterns; early exit when count == KNN ----
    uint32_t bound = 0u;
    bool     found = false;
    while (hi - lo > 1u) {
        const uint32_t mid = lo + ((hi - lo) >> 1);
        uint32_t c = 0;
        #pragma unroll
        for (int j = 0; j < 32; ++j)
            c += (uint32_t)__builtin_popcountll(__ballot(db[j] <= mid));
        if (c == KNN) { bound = mid; found = true; break; }
        if (c > KNN) hi = mid; else lo = mid;
    }

    if (found) {
        // exact top-32 set is {v <= bound}; order-free compaction
        uint32_t base = 0;
        #pragma unroll
        for (int j = 0; j < 32; ++j) {
            const uint64_t m = __ballot(db[j] <= bound);
            if (db[j] <= bound) {
                const int slot = (int)base + (int)__popcll(m & lmlt);
                sel[w][slot] = lane + (j << 6);
            }
            base += (uint32_t)__builtin_popcountll(m);
        }
    } else {
        // exact-tie fallback: T = hi; all <T, then ==T in ascending-n order
        const uint32_t T = hi;
        uint32_t cl = 0;
        #pragma unroll
        for (int j = 0; j < 32; ++j)
            cl += (uint32_t)__builtin_popcountll(__ballot(db[j] <= lo));
        const int cnt_lt = (int)cl;
        int base_lt = 0, base_eq = 0;
        #pragma unroll
        for (int j = 0; j < 32; ++j) {
            const bool lt = db[j] < T;
            const bool eq = db[j] == T;
            const uint64_t mlt = __ballot(lt);
            const uint64_t meq = __ballot(eq);
            int slot = -1;
            if (lt)      slot = base_lt + (int)__popcll(mlt & lmlt);
            else if (eq) slot = cnt_lt + base_eq + (int)__popcll(meq & lmlt);
            if (slot >= 0 && slot < KNN) sel[w][slot] = lane + (j << 6);
            base_lt += (int)__popcll(mlt);
            base_eq += (int)__popcll(meq);
        }
    }

    // ---- gather + max-pool: one LDS read, then readlane broadcasts ----
    const int selv = sel[w][lane & (KNN - 1)];

    float4 a0 = make_float4(-INFINITY, -INFINITY, -INFINITY, -INFINITY);
    float4 a1 = a0;
    #pragma unroll 8
    for (int k = 0; k < KNN; ++k) {
        const int nb = __builtin_amdgcn_readlane(selv, k) & (NPTS - 1);
        const float4* row = (const float4*)(xb + (size_t)nb * NF);
        const float4 v0 = row[lane];
        const float4 v1 = row[lane + 64];
        a0.x = fmaxf(a0.x, v0.x);  a0.y = fmaxf(a0.y, v0.y);
        a0.z = fmaxf(a0.z, v0.z);  a0.w = fmaxf(a0.w, v0.w);
        a1.x = fmaxf(a1.x, v1.x);  a1.y = fmaxf(a1.y, v1.y);
        a1.z = fmaxf(a1.z, v1.z);  a1.w = fmaxf(a1.w, v1.w);
    }

    // ---- nontemporal stores: no L2 write-allocate, keep x[b] resident ----
    vfloat4* orow = (vfloat4*)(out + ((size_t)b * NPTS + i) * NF);
    const vfloat4 na0 = vfloat4{a0.x, a0.y, a0.z, a0.w};
    const vfloat4 na1 = vfloat4{a1.x, a1.y, a1.z, a1.w};
    __builtin_nontemporal_store(na0, &orow[lane]);
    __builtin_nontemporal_store(na1, &orow[lane + 64]);
}

extern "C" void kernel_launch(void* const* d_in, const int* in_sizes, int n_in,
                              void* d_out, int out_size, void* d_ws, size_t ws_size,
                              hipStream_t stream) {
    const float* x      = (const float*)d_in[0];   // [8, 2048, 512] f32
    const float* points = (const float*)d_in[1];   // [8, 2048, 3]   f32
    float* out          = (float*)d_out;           // [8, 2048, 512] f32

    pointnetpp_knn_maxpool<<<dim3(BATCHES * (NPTS / WAVES)),
                             dim3(512), 0, stream>>>(x, points, out);
}

// Round 9
// 128.156 us; speedup vs baseline: 1.7566x; 1.0471x over previous
//
#include <hip/hip_runtime.h>
#include <cstdint>

#define BATCHES 8
#define NPTS 2048
#define NF 512
#define KNN 32
#define WAVES 8   // 512-thread block = 8 waves, ONE query per wave

// grid = 8 batches * 256 chunks = 2048 blocks; batch = blockIdx & 7 (XCD L2 affinity)
// LDS = 32768 (pts4) + 4096 (ckey) + 1024 (sel) = 37888 B -> 4 blocks = 148 KB < 160.
// (512,4): loose reg cap; tight caps scratch-spill db[32] (R4 evidence).

typedef float vfloat4 __attribute__((ext_vector_type(4)));  // native vec for nt-store

__global__ __launch_bounds__(512, 4)
void pointnetpp_knn_maxpool(const float* __restrict__ x,
                            const float* __restrict__ points,
                            float* __restrict__ out) {
    __shared__ __align__(16) float    pts4[NPTS * 4];    // [N][4]: one b128/candidate
    __shared__ __align__(16) uint64_t ckey[WAVES][64];   // candidate keys (fast path)
    __shared__ __align__(16) int      sel[WAVES][KNN];   // fallback emit only

    const int tid  = threadIdx.x;
    const int lane = tid & 63;
    const int w    = tid >> 6;

    const int b     = blockIdx.x & 7;
    const int chunk = blockIdx.x >> 3;

    // ---- stage points[b] into LDS as [N][4] (pad .w) ----
    {
        const float* src = points + (size_t)b * NPTS * 3;
        for (int p = tid; p < NPTS; p += 512) {
            float4* d = (float4*)&pts4[p * 4];
            *d = make_float4(src[p * 3 + 0], src[p * 3 + 1], src[p * 3 + 2], 0.f);
        }
    }
    __syncthreads();

    const uint64_t lmlt = (1ull << lane) - 1ull;
    const float*   xb   = x + (size_t)b * NPTS * NF;

    const int i = chunk * WAVES + w;   // this wave's query

    const float4 qp = *(const float4*)&pts4[i * 4];

    // ---- squared distances (bit patterns; arithmetic identical to R1..R8) ----
    uint32_t db[32];
    #pragma unroll
    for (int j = 0; j < 32; ++j) {
        const int n = lane + (j << 6);
        const float4 pp = *(const float4*)&pts4[n * 4];
        const float dx = qp.x - pp.x;
        const float dy = qp.y - pp.y;
        const float dz = qp.z - pp.z;
        db[j] = __float_as_uint(dx * dx + dy * dy + dz * dz);
    }

    auto countLE = [&](uint32_t t) {
        uint32_t c = 0;
        #pragma unroll
        for (int j = 0; j < 32; ++j)
            c += (uint32_t)__builtin_popcountll(__ballot(db[j] <= t));
        return c;
    };

    // ---- seed hi = wave_max(per-lane min): count(<=hi) >= 64 ----
    uint32_t lmin = db[0];
    #pragma unroll
    for (int j = 1; j < 32; ++j) lmin = min(lmin, db[j]);
    uint32_t hi = lmin;
    #pragma unroll
    for (int m = 1; m < 64; m <<= 1)
        hi = max(hi, (uint32_t)__shfl_xor((int)hi, m));
    uint32_t lo = 0u;   // count(<=0) = 1 (self) < KNN

    // ---- window search: any thr with 32 <= count(<=thr) <= 64 ----
    uint32_t thr = 0u, cthr = 0u;
    bool     have = false;
    {
        const uint32_t cs = countLE(hi);   // >= 64 by construction
        if (cs <= 64u) { thr = hi; cthr = cs; have = true; }
    }
    while (!have && hi - lo > 1u) {
        const uint32_t mid = lo + ((hi - lo) >> 1);
        const uint32_t c   = countLE(mid);
        if (c >= KNN && c <= 64u) { thr = mid; cthr = c; have = true; break; }
        if (c > 64u) hi = mid; else lo = mid;
    }

    int selv;   // per-lane: lanes 0..31 hold the 32 selected indices
    if (have) {
        // ---- compact <=64 candidates to LDS as 43-bit keys (d2<<11 | idx) ----
        uint32_t base = 0;
        #pragma unroll
        for (int j = 0; j < 32; ++j) {
            const bool     p = db[j] <= thr;
            const uint64_t m = __ballot(p);
            if (p) {
                const int slot = (int)base + (int)__popcll(m & lmlt);
                ckey[w][slot] = (((uint64_t)db[j]) << 11) | (uint64_t)(lane + (j << 6));
            }
            base += (uint32_t)__builtin_popcountll(m);
        }
        uint64_t key = (lane < (int)cthr) ? ckey[w][lane] : ~0ull;

        // ---- wave bitonic sort64 ascending on (d2, idx) ----
        #pragma unroll
        for (int k = 2; k <= 64; k <<= 1) {
            #pragma unroll
            for (int j = k >> 1; j > 0; j >>= 1) {
                const uint64_t other = __shfl_xor((unsigned long long)key, j);
                const bool takeMin = (((lane & j) == 0) == ((lane & k) == 0));
                const uint64_t mn = key < other ? key : other;
                const uint64_t mx = key < other ? other : key;
                key = takeMin ? mn : mx;
            }
        }
        selv = (int)(key & 0x7FFull);   // lanes 0..31: exact top-32 (ref tie order)
    } else {
        // ---- exact-tie fallback: T = hi; all <T, then ==T ascending-n ----
        const uint32_t T = hi;
        const int cnt_lt = (int)countLE(lo);   // count(<T)
        int base_lt = 0, base_eq = 0;
        #pragma unroll
        for (int j = 0; j < 32; ++j) {
            const bool lt = db[j] < T;
            const bool eq = db[j] == T;
            const uint64_t mlt = __ballot(lt);
            const uint64_t meq = __ballot(eq);
            int slot = -1;
            if (lt)      slot = base_lt + (int)__popcll(mlt & lmlt);
            else if (eq) slot = cnt_lt + base_eq + (int)__popcll(meq & lmlt);
            if (slot >= 0 && slot < KNN) sel[w][slot] = lane + (j << 6);
            base_lt += (int)__popcll(mlt);
            base_eq += (int)__popcll(meq);
        }
        selv = sel[w][lane & (KNN - 1)];
    }

    // ---- gather + max-pool: readlane broadcasts, float4 coalesced ----
    float4 a0 = make_float4(-INFINITY, -INFINITY, -INFINITY, -INFINITY);
    float4 a1 = a0;
    #pragma unroll 8
    for (int k = 0; k < KNN; ++k) {
        const int nb = __builtin_amdgcn_readlane(selv, k) & (NPTS - 1);
        const float4* row = (const float4*)(xb + (size_t)nb * NF);
        const float4 v0 = row[lane];
        const float4 v1 = row[lane + 64];
        a0.x = fmaxf(a0.x, v0.x);  a0.y = fmaxf(a0.y, v0.y);
        a0.z = fmaxf(a0.z, v0.z);  a0.w = fmaxf(a0.w, v0.w);
        a1.x = fmaxf(a1.x, v1.x);  a1.y = fmaxf(a1.y, v1.y);
        a1.z = fmaxf(a1.z, v1.z);  a1.w = fmaxf(a1.w, v1.w);
    }

    // ---- nontemporal stores: no L2 write-allocate, keep x[b] resident ----
    vfloat4* orow = (vfloat4*)(out + ((size_t)b * NPTS + i) * NF);
    const vfloat4 na0 = vfloat4{a0.x, a0.y, a0.z, a0.w};
    const vfloat4 na1 = vfloat4{a1.x, a1.y, a1.z, a1.w};
    __builtin_nontemporal_store(na0, &orow[lane]);
    __builtin_nontemporal_store(na1, &orow[lane + 64]);
}

extern "C" void kernel_launch(void* const* d_in, const int* in_sizes, int n_in,
                              void* d_out, int out_size, void* d_ws, size_t ws_size,
                              hipStream_t stream) {
    const float* x      = (const float*)d_in[0];   // [8, 2048, 512] f32
    const float* points = (const float*)d_in[1];   // [8, 2048, 3]   f32
    float* out          = (float*)d_out;           // [8, 2048, 512] f32

    pointnetpp_knn_maxpool<<<dim3(BATCHES * (NPTS / WAVES)),
                             dim3(512), 0, stream>>>(x, points, out);
}